// Round 14
// baseline (8467.981 us; speedup 1.0000x reference)
//
#include <hip/hip_runtime.h>

#define T_TOK 4096
#define HID   4096
#define IMD   11008

using f32x4  = __attribute__((ext_vector_type(4))) float;
using bf16x8 = __attribute__((ext_vector_type(8))) __bf16;
union FragCast { int4 i; bf16x8 b; };

__device__ __forceinline__ unsigned f2bf_bits(float f) {
  unsigned u = __float_as_uint(f);
  return (u + 0x7fffu + ((u >> 16) & 1u)) >> 16;   // RNE f32 -> bf16
}
__device__ __forceinline__ float bf2f(short s) {
  return __uint_as_float(((unsigned)(unsigned short)s) << 16);
}
__device__ __forceinline__ int4 cvt8(const float4 f0, const float4 f1) {
  int4 r;
  r.x = f2bf_bits(f0.x) | (f2bf_bits(f0.y) << 16);
  r.y = f2bf_bits(f0.z) | (f2bf_bits(f0.w) << 16);
  r.z = f2bf_bits(f1.x) | (f2bf_bits(f1.y) << 16);
  r.w = f2bf_bits(f1.z) | (f2bf_bits(f1.w) << 16);
  return r;
}
__device__ __forceinline__ void gload16(const void* g, void* l) {
  __builtin_amdgcn_global_load_lds(
      (__attribute__((address_space(1))) void*)g,
      (__attribute__((address_space(3))) void*)l, 16, 0, 0);
}

// ---------------------------------------------------------------- prep kernels
__global__ void cvt_pad(const float* __restrict__ in, short* __restrict__ out,
                        int C8, int CT, long ldin, long ldout) {
  long r = blockIdx.x;
  const float4* s = (const float4*)(in + r * ldin);
  int4* d = (int4*)(out + r * ldout);
  for (int c = threadIdx.x; c < CT; c += blockDim.x)
    d[c] = (c < C8) ? cvt8(s[2 * c], s[2 * c + 1]) : int4{0, 0, 0, 0};
}

__global__ void build_wbT_pad(const float* __restrict__ wb,
                              short* __restrict__ out, int N, long ldout,
                              long K) {
  int n = blockIdx.x * blockDim.x + threadIdx.x;
  int ar = blockIdx.y;
  if (n < N) out[(long)n * ldout + K + ar] = (short)f2bf_bits(wb[(long)ar * N + n]);
}

// per-token rank projection: out[t][a*16+r] = mask * sum_h Abf[t][h]*wa[a][h][r]
template <int KD, int NOUT>
__global__ __launch_bounds__(256)
void lora_proj(const short* __restrict__ Abf, long ldA,
               const float* __restrict__ wa0, const float* __restrict__ wa1,
               const int* __restrict__ seg, short* out0, long ld0, short* out1,
               long ld1) {
  __shared__ __align__(16) short rowbuf[KD];
  __shared__ float part[NOUT][4][16];
  int t = blockIdx.x, tid = threadIdx.x;
  int a = seg[t];
  const int4* src = (const int4*)(Abf + (long)t * ldA);
  for (int c = tid; c < KD / 8; c += 256) ((int4*)rowbuf)[c] = src[c];
  __syncthreads();
  int w = tid >> 6, l = tid & 63;
  int r = l & 15, g = l >> 4;
  const int HW = KD / 4;
  float s0 = 0.f, s1 = 0.f;
  const float* p0 = wa0 + (long)a * KD * 16 + r;
  const float* p1 = (NOUT == 2) ? (wa1 + (long)a * KD * 16 + r) : nullptr;
  int h = w * HW + g;
  for (int k = 0; k < HW / 4; ++k, h += 4) {
    float xv = bf2f(rowbuf[h]);
    s0 = fmaf(xv, p0[(long)h * 16], s0);
    if (NOUT == 2) s1 = fmaf(xv, p1[(long)h * 16], s1);
  }
  s0 += __shfl_xor(s0, 16); s0 += __shfl_xor(s0, 32);
  if (NOUT == 2) { s1 += __shfl_xor(s1, 16); s1 += __shfl_xor(s1, 32); }
  if (l < 16) { part[0][w][r] = s0; if (NOUT == 2) part[1][w][r] = s1; }
  __syncthreads();
  if (tid < 64 * NOUT) {
    int m = tid >> 6, ar = tid & 63;
    float v = 0.f;
    if ((ar >> 4) == a) {
      int r2 = ar & 15;
      v = part[m][0][r2] + part[m][1][r2] + part[m][2][r2] + part[m][3][r2];
    }
    short b = (short)f2bf_bits(v);
    if (m == 0) out0[(long)t * ld0 + ar] = b;
    else        out1[(long)t * ld1 + ar] = b;
  }
}

// -------- gate/up GEMM: BK=32, 80KB LDS, 2 BLOCKS/CU (4 waves/SIMD TLP)
// 256x256 tile, 8 waves 2Mx4N, per-wave 128x64 (same reuse ratio as BK=64).
// LDS: A ring 3x16KB @0/16384/32768; B dbuf 2x16KB @49152/65536 = 80KB ->
// 2 resident blocks/CU; cross-block MFMA||LDS overlap (m114) replaces the
// intra-block pipelining that 2-waves/SIMD could not express (R4-R13 plateau).
// Per K-step (K=32), 2 phases, single barrier each (R13 discipline):
//  ph0: read bF[4]+aF[mi0-3] (8xb128) | stage B(t+1) | BAR | 16 MFMA
//  ph1: read aF[mi4-7] (4xb128) | stage A(t+2) | vmcnt(2) | BAR | 16 MFMA
// Wait audit (2 gloads per stage call): queue at ph1 wait =
// [A(t+1)2, B(t+1)2, A(t+2)2] -> vmcnt(2) confirms what iter t+1 ph0 reads,
// keeps A(t+2) in flight; drains to 0 only at t >= iters-2. WAR: every LDS
// region's overwrite is >=2 collective barriers after its last read (lgkm
// drain for reads precedes the reader's next-phase MFMA which precedes the
// barrier the writer must pass; skew bound 1 phase).
// LDS slot map (BK=32 rows are 64B -> linear layout would 4-way conflict):
// global chunk (r, c2) [16B, c2=0..3] stored at slot s = (r>>2)*16 +
// (r&3)*4 + c2. Read lane (lrow,lhi) of row R=base+mi*16+lrow needs chunk
// (R, lhi) -> 64 lanes hit 64 DISTINCT slots covering one contiguous 1KB
// block: conflict-free. Staging: thread t fetches (r=((t>>4)<<2)|((t>>2)&3),
// c2=t&3); slots t, t+512 (row+128). Global access = 64B runs (coalesced).
template <int MODE>  // 0: bf16 store; 1: silu(gbuf)*acc -> bf16 in-place
__global__ __launch_bounds__(512, 4)
void gemm_gu32(const short* __restrict__ A, const short* __restrict__ B,
               const short* __restrict__ gbuf, short* __restrict__ outB,
               int nby, long ldK, int iters, long ldo) {
  extern __shared__ __align__(16) char smem[];

  int nwg = gridDim.x;
  int orig = blockIdx.x;
  int q = nwg >> 3, rr = nwg & 7;
  int xcd = orig & 7, loc = orig >> 3;
  int swz = (xcd < rr ? xcd * (q + 1) : rr * (q + 1) + (xcd - rr) * q) + loc;
  int bx = swz & 15, by = swz >> 4;     // bx-fastest: B col-panel L2-resident
  long row0 = (long)bx * 256, col0 = (long)by * 256;

  int tid = threadIdx.x;
  int l = tid & 63, wid = tid >> 6;
  int wr = wid >> 2, wc = wid & 3;      // 2M x 4N waves, 128x64 each
  int lrow = l & 15, lhi = l >> 4;

  // staging source: thread t -> global chunk (r, c2); slots t and t+512
  int sr = ((tid >> 4) << 2) | ((tid >> 2) & 3);
  int sc = tid & 3;
  const short* pA0 = A + (row0 + sr) * ldK + sc * 8;
  const short* pB0 = B + (col0 + sr) * ldK + sc * 8;
  const long d128 = (long)128 * ldK;    // slot t+512 = row sr+128, same c2

  auto stA = [&](int bi, int kt) {
    char* d = smem + bi * 16384 + tid * 16;
    const short* s = pA0 + (long)kt * 32;
    gload16(s, d);
    gload16(s + d128, d + 8192);
  };
  auto stB = [&](int bi, int kt) {
    char* d = smem + 49152 + bi * 16384 + tid * 16;
    const short* s = pB0 + (long)kt * 32;
    gload16(s, d);
    gload16(s + d128, d + 8192);
  };

  f32x4 acc[8][4];
  f32x4 zr = {0.f, 0.f, 0.f, 0.f};
#pragma unroll
  for (int mi = 0; mi < 8; ++mi)
#pragma unroll
    for (int ni = 0; ni < 4; ++ni) acc[mi][ni] = zr;

  // read bases: byte = 16*[ (R>>2)*16 + (R&3)*4 + lhi ], R = rowbase+mi*16+lrow
  const int aBase = wr * 8192 + (lrow >> 2) * 256 + (lrow & 3) * 64 + lhi * 16;
  const int bBase = wc * 4096 + (lrow >> 2) * 256 + (lrow & 3) * 64 + lhi * 16;

  // prologue: A(0), B(0), A(1); confirm A(0),B(0); A(1) stays in flight
  stA(0, 0); stB(0, 0); stA(1, 1);
  asm volatile("s_waitcnt vmcnt(2)" ::: "memory");
  asm volatile("s_barrier" ::: "memory");

  int ca = 0;
#pragma unroll 1
  for (int t = 0; t < iters; ++t) {
    const char* Ab = smem + ca * 16384;
    const char* Bb = smem + 49152 + (t & 1) * 16384;
    int na2 = (ca >= 1) ? ca - 1 : 2;   // (ca+2)%3: buffer for A(t+2)
    int nb1 = (t + 1) & 1;

    // ph0: bF + aF(mi 0-3); stage B(t+1); BAR; 16 MFMA
    bf16x8 bF[4], aF[4];
#pragma unroll
    for (int ni = 0; ni < 4; ++ni) {
      FragCast f; f.i = *(const int4*)(Bb + bBase + ni * 1024);
      bF[ni] = f.b;
    }
#pragma unroll
    for (int mi = 0; mi < 4; ++mi) {
      FragCast f; f.i = *(const int4*)(Ab + aBase + mi * 1024);
      aF[mi] = f.b;
    }
    if (t + 1 < iters) stB(nb1, t + 1);
    asm volatile("s_barrier" ::: "memory");
    __builtin_amdgcn_s_setprio(1);
#pragma unroll
    for (int mi = 0; mi < 4; ++mi)
#pragma unroll
      for (int ni = 0; ni < 4; ++ni)
        acc[mi][ni] = __builtin_amdgcn_mfma_f32_16x16x32_bf16(
            aF[mi], bF[ni], acc[mi][ni], 0, 0, 0);
    __builtin_amdgcn_s_setprio(0);

    // ph1: aF(mi 4-7); stage A(t+2); counted wait; BAR; 16 MFMA
    bf16x8 aG[4];
#pragma unroll
    for (int mi = 0; mi < 4; ++mi) {
      FragCast f; f.i = *(const int4*)(Ab + aBase + (4 + mi) * 1024);
      aG[mi] = f.b;
    }
    if (t + 2 < iters) {
      stA(na2, t + 2);
      asm volatile("s_waitcnt vmcnt(2)" ::: "memory");
    } else {
      asm volatile("s_waitcnt vmcnt(0)" ::: "memory");
    }
    asm volatile("s_barrier" ::: "memory");
    __builtin_amdgcn_s_setprio(1);
#pragma unroll
    for (int mi = 0; mi < 4; ++mi)
#pragma unroll
      for (int ni = 0; ni < 4; ++ni)
        acc[4 + mi][ni] = __builtin_amdgcn_mfma_f32_16x16x32_bf16(
            aG[mi], bF[ni], acc[4 + mi][ni], 0, 0, 0);
    __builtin_amdgcn_s_setprio(0);

    ca = (ca == 2) ? 0 : ca + 1;
  }

  // epilogue: C/D layout col=lane&15, row=(lane>>4)*4+reg  [m89]
#pragma unroll
  for (int mi = 0; mi < 8; ++mi)
#pragma unroll
    for (int ni = 0; ni < 4; ++ni)
#pragma unroll
      for (int j = 0; j < 4; ++j) {
        long grow = row0 + wr * 128 + mi * 16 + lhi * 4 + j;
        long gcol = col0 + wc * 64 + ni * 16 + lrow;
        long idx = grow * ldo + gcol;
        float v = acc[mi][ni][j];
        if constexpr (MODE == 0) {
          outB[idx] = (short)f2bf_bits(v);
        } else {
          float g = bf2f(gbuf[idx]);
          float t2 = g * (1.f / (1.f + __expf(-g))) * v;   // silu(g)*u
          outB[idx] = (short)f2bf_bits(t2);
        }
      }
}

// --------------------- down GEMM: R13 control (4-phase BK=64, 1 block/CU)
__global__ __launch_bounds__(512, 2)
void gemm_down(const short* __restrict__ A, const short* __restrict__ B,
               float* outF, int nby, long ldK, int iters, long ldo) {
  extern __shared__ __align__(16) char smem[];

  int nwg = gridDim.x;
  int orig = blockIdx.x;
  int q = nwg >> 3, rr = nwg & 7;
  int xcd = orig & 7, loc = orig >> 3;
  int swz = (xcd < rr ? xcd * (q + 1) : rr * (q + 1) + (xcd - rr) * q) + loc;
  int by = swz % nby, bx = swz / nby;
  long row0 = (long)bx * 256, col0 = (long)by * 256;

  int tid = threadIdx.x;
  int l = tid & 63, wid = tid >> 6;
  int wr = wid >> 2, wc = wid & 3;
  int lrow = l & 15, lhi = l >> 4, md = lrow & 7;

  const short* aP[4]; const short* bP[4];
  int dst[4];
#pragma unroll
  for (int k = 0; k < 4; ++k) {
    int idx = tid + k * 512;
    int r = idx >> 3, c8 = idx & 7;
    aP[k] = A + (row0 + r) * ldK + (c8 ^ (r & 7)) * 8;
    bP[k] = B + (col0 + r) * ldK + (c8 ^ (r & 7)) * 8;
    dst[k] = idx * 16;
  }

  auto stageA_h = [&](int bi, int h) {
    char* d = smem + bi * 32768;
    gload16(aP[2 * h], d + dst[2 * h]);         aP[2 * h] += 64;
    gload16(aP[2 * h + 1], d + dst[2 * h + 1]); aP[2 * h + 1] += 64;
  };
  auto stageB_h = [&](int bi, int h) {
    char* d = smem + 98304 + bi * 32768;
    gload16(bP[2 * h], d + dst[2 * h]);         bP[2 * h] += 64;
    gload16(bP[2 * h + 1], d + dst[2 * h + 1]); bP[2 * h + 1] += 64;
  };

  f32x4 acc[8][4];
  f32x4 zr = {0.f, 0.f, 0.f, 0.f};
#pragma unroll
  for (int mi = 0; mi < 8; ++mi)
#pragma unroll
    for (int ni = 0; ni < 4; ++ni) acc[mi][ni] = zr;

  const int csel0 = (lhi ^ md) * 16;
  const int csel1 = ((4 + lhi) ^ md) * 16;

  stageA_h(0, 0); stageA_h(0, 1);
  stageB_h(0, 0); stageB_h(0, 1);
  stageA_h(1, 0); stageA_h(1, 1);
  asm volatile("s_waitcnt vmcnt(4)" ::: "memory");
  asm volatile("s_barrier" ::: "memory");

  int ca = 0;
#pragma unroll 1
  for (int t = 0; t < iters; ++t) {
    const char* Ab = smem + ca * 32768;
    const char* Bb = smem + 98304 + (t & 1) * 32768;
    int na2 = (ca >= 1) ? ca - 1 : 2;
    int nb1 = (t + 1) & 1;
    bf16x8 bF[4][2];

#pragma unroll
    for (int p = 0; p < 4; ++p) {
      if (p == 0) {
#pragma unroll
        for (int ni = 0; ni < 4; ++ni) {
          const char* base = Bb + (wc * 64 + ni * 16 + lrow) * 128;
          FragCast f0, f1;
          f0.i = *(const int4*)(base + csel0);
          f1.i = *(const int4*)(base + csel1);
          bF[ni][0] = f0.b; bF[ni][1] = f1.b;
        }
      }
      bf16x8 aF[2][2];
#pragma unroll
      for (int m2 = 0; m2 < 2; ++m2) {
        const char* base = Ab + (wr * 128 + p * 32 + m2 * 16 + lrow) * 128;
        FragCast f0, f1;
        f0.i = *(const int4*)(base + csel0);
        f1.i = *(const int4*)(base + csel1);
        aF[m2][0] = f0.b; aF[m2][1] = f1.b;
      }
      if (p == 0 && t + 1 < iters) stageB_h(nb1, 0);
      if (p == 1 && t + 1 < iters) stageB_h(nb1, 1);
      if (p == 2 && t + 2 < iters) stageA_h(na2, 0);
      if (p == 3) {
        if (t + 2 < iters) {
          stageA_h(na2, 1);
          asm volatile("s_waitcnt vmcnt(4)" ::: "memory");
        } else {
          asm volatile("s_waitcnt vmcnt(0)" ::: "memory");
        }
      }
      asm volatile("s_barrier" ::: "memory");
      __builtin_amdgcn_s_setprio(1);
#pragma unroll
      for (int k = 0; k < 2; ++k)
#pragma unroll
        for (int m2 = 0; m2 < 2; ++m2)
#pragma unroll
          for (int ni = 0; ni < 4; ++ni)
            acc[p * 2 + m2][ni] = __builtin_amdgcn_mfma_f32_16x16x32_bf16(
                aF[m2][k], bF[ni][k], acc[p * 2 + m2][ni], 0, 0, 0);
      __builtin_amdgcn_s_setprio(0);
    }
    ca = (ca == 2) ? 0 : ca + 1;
  }

#pragma unroll
  for (int mi = 0; mi < 8; ++mi)
#pragma unroll
    for (int ni = 0; ni < 4; ++ni)
#pragma unroll
      for (int j = 0; j < 4; ++j) {
        long grow = row0 + wr * 128 + mi * 16 + lhi * 4 + j;
        long gcol = col0 + wc * 64 + ni * 16 + lrow;
        outF[grow * ldo + gcol] = acc[mi][ni][j];
      }
}

// ---------------------------------------------------------------- launcher
extern "C" void kernel_launch(void* const* d_in, const int* in_sizes, int n_in,
                              void* d_out, int out_size, void* d_ws,
                              size_t ws_size, hipStream_t stream) {
  const float* x       = (const float*)d_in[0];
  const float* gate_w  = (const float*)d_in[1];
  const float* up_w    = (const float*)d_in[2];
  const float* down_w  = (const float*)d_in[3];
  const float* gate_wa = (const float*)d_in[4];
  const float* gate_wb = (const float*)d_in[5];
  const float* up_wa   = (const float*)d_in[6];
  const float* up_wb   = (const float*)d_in[7];
  const float* down_wa = (const float*)d_in[8];
  const float* down_wb = (const float*)d_in[9];
  const int*   seg     = (const int*)d_in[10];

  // ldK gate/up = 4096+128 = 4224 (BK=32 -> iters=132); down = 11072 (173)
  char* ws = (char*)d_ws;
  short* xg_pad = (short*)(ws);                   // [4096][4224]  34.6 MB
  short* wA     = (short*)(ws + 34603008);        // gate_w pad -> down_w pad
  short* wB     = (short*)(ws + 127598592);       // up_w pad     93.0 MB
  short* t_pad  = (short*)(ws + 220594176);       // [4096][11072] 90.7 MB

  const int LDS_GU = 81920;    // A 3x16K + B 2x16K  -> 2 blocks/CU
  const int LDS_D  = 163840;   // A 3x32K + B 2x32K
  hipFuncSetAttribute(reinterpret_cast<const void*>(&gemm_gu32<0>),
                      hipFuncAttributeMaxDynamicSharedMemorySize, LDS_GU);
  hipFuncSetAttribute(reinterpret_cast<const void*>(&gemm_gu32<1>),
                      hipFuncAttributeMaxDynamicSharedMemorySize, LDS_GU);
  hipFuncSetAttribute(reinterpret_cast<const void*>(&gemm_down),
                      hipFuncAttributeMaxDynamicSharedMemorySize, LDS_D);

  // bf16 padded operand build (cvt_pad zero-fills the 128-col LoRA tail of
  // the weight matrices; build_wbT then overwrites its 64-col band)
  cvt_pad<<<T_TOK, 256, 0, stream>>>(x, xg_pad, 512, 512, HID, 4224);
  cvt_pad<<<IMD, 256, 0, stream>>>(gate_w, wA, 512, 528, HID, 4224);
  cvt_pad<<<IMD, 256, 0, stream>>>(up_w, wB, 512, 528, HID, 4224);
  build_wbT_pad<<<dim3(43, 64), 256, 0, stream>>>(gate_wb, wA, IMD, 4224, 4096);
  build_wbT_pad<<<dim3(43, 64), 256, 0, stream>>>(up_wb, wB, IMD, 4224, 4160);
  lora_proj<HID, 2><<<T_TOK, 256, 0, stream>>>(
      xg_pad, 4224, gate_wa, up_wa, seg, xg_pad + 4096, 4224, xg_pad + 4160,
      4224);

  // gate: t_pad = x @ gate_w^T + lora_g   (BK=32, 2 blocks/CU)
  gemm_gu32<0><<<16 * 43, 512, LDS_GU, stream>>>(
      xg_pad, wA, nullptr, t_pad, 43, 4224, 132, 11072);
  // up: t_pad = silu(t_pad) * (x @ up_w^T + lora_u), in place
  gemm_gu32<1><<<16 * 43, 512, LDS_GU, stream>>>(
      xg_pad, wB, t_pad, t_pad, 43, 4224, 132, 11072);

  // down operand build (wA region free after gate GEMM)
  cvt_pad<<<T_TOK, 256, 0, stream>>>(down_w, wA, 1376, 1376, IMD, 11072);
  build_wbT_pad<<<dim3(16, 64), 256, 0, stream>>>(down_wb, wA, HID, 11072,
                                                  IMD);
  lora_proj<IMD, 1><<<T_TOK, 256, 0, stream>>>(
      t_pad, 11072, down_wa, nullptr, seg, t_pad + IMD, 11072, nullptr, 64);

  // down: out = t @ down_w^T + lora   [M=4096, N=4096, K'=11072]
  gemm_down<<<16 * 16, 512, LDS_D, stream>>>(t_pad, wA, (float*)d_out, 16,
                                             11072, 173, 4096);
}

// Round 15
// 2994.959 us; speedup vs baseline: 2.8274x; 2.8274x over previous
//
#include <hip/hip_runtime.h>

#define T_TOK 4096
#define HID   4096
#define IMD   11008

using f32x4  = __attribute__((ext_vector_type(4))) float;
using bf16x8 = __attribute__((ext_vector_type(8))) __bf16;
union FragCast { int4 i; bf16x8 b; };

__device__ __forceinline__ unsigned f2bf_bits(float f) {
  unsigned u = __float_as_uint(f);
  return (u + 0x7fffu + ((u >> 16) & 1u)) >> 16;   // RNE f32 -> bf16
}
__device__ __forceinline__ float bf2f(short s) {
  return __uint_as_float(((unsigned)(unsigned short)s) << 16);
}
__device__ __forceinline__ int4 cvt8(const float4 f0, const float4 f1) {
  int4 r;
  r.x = f2bf_bits(f0.x) | (f2bf_bits(f0.y) << 16);
  r.y = f2bf_bits(f0.z) | (f2bf_bits(f0.w) << 16);
  r.z = f2bf_bits(f1.x) | (f2bf_bits(f1.y) << 16);
  r.w = f2bf_bits(f1.z) | (f2bf_bits(f1.w) << 16);
  return r;
}
__device__ __forceinline__ void gload16(const void* g, void* l) {
  __builtin_amdgcn_global_load_lds(
      (__attribute__((address_space(1))) void*)g,
      (__attribute__((address_space(3))) void*)l, 16, 0, 0);
}

// ---------------------------------------------------------------- prep kernels
__global__ void cvt_pad(const float* __restrict__ in, short* __restrict__ out,
                        int C8, int CT, long ldin, long ldout) {
  long r = blockIdx.x;
  const float4* s = (const float4*)(in + r * ldin);
  int4* d = (int4*)(out + r * ldout);
  for (int c = threadIdx.x; c < CT; c += blockDim.x)
    d[c] = (c < C8) ? cvt8(s[2 * c], s[2 * c + 1]) : int4{0, 0, 0, 0};
}

__global__ void build_wbT_pad(const float* __restrict__ wb,
                              short* __restrict__ out, int N, long ldout,
                              long K) {
  int n = blockIdx.x * blockDim.x + threadIdx.x;
  int ar = blockIdx.y;
  if (n < N) out[(long)n * ldout + K + ar] = (short)f2bf_bits(wb[(long)ar * N + n]);
}

// per-token rank projection: out[t][a*16+r] = mask * sum_h Abf[t][h]*wa[a][h][r]
template <int KD, int NOUT>
__global__ __launch_bounds__(256)
void lora_proj(const short* __restrict__ Abf, long ldA,
               const float* __restrict__ wa0, const float* __restrict__ wa1,
               const int* __restrict__ seg, short* out0, long ld0, short* out1,
               long ld1) {
  __shared__ __align__(16) short rowbuf[KD];
  __shared__ float part[NOUT][4][16];
  int t = blockIdx.x, tid = threadIdx.x;
  int a = seg[t];
  const int4* src = (const int4*)(Abf + (long)t * ldA);
  for (int c = tid; c < KD / 8; c += 256) ((int4*)rowbuf)[c] = src[c];
  __syncthreads();
  int w = tid >> 6, l = tid & 63;
  int r = l & 15, g = l >> 4;
  const int HW = KD / 4;
  float s0 = 0.f, s1 = 0.f;
  const float* p0 = wa0 + (long)a * KD * 16 + r;
  const float* p1 = (NOUT == 2) ? (wa1 + (long)a * KD * 16 + r) : nullptr;
  int h = w * HW + g;
  for (int k = 0; k < HW / 4; ++k, h += 4) {
    float xv = bf2f(rowbuf[h]);
    s0 = fmaf(xv, p0[(long)h * 16], s0);
    if (NOUT == 2) s1 = fmaf(xv, p1[(long)h * 16], s1);
  }
  s0 += __shfl_xor(s0, 16); s0 += __shfl_xor(s0, 32);
  if (NOUT == 2) { s1 += __shfl_xor(s1, 16); s1 += __shfl_xor(s1, 32); }
  if (l < 16) { part[0][w][r] = s0; if (NOUT == 2) part[1][w][r] = s1; }
  __syncthreads();
  if (tid < 64 * NOUT) {
    int m = tid >> 6, ar = tid & 63;
    float v = 0.f;
    if ((ar >> 4) == a) {
      int r2 = ar & 15;
      v = part[m][0][r2] + part[m][1][r2] + part[m][2][r2] + part[m][3][r2];
    }
    short b = (short)f2bf_bits(v);
    if (m == 0) out0[(long)t * ld0 + ar] = b;
    else        out1[(long)t * ld1 + ar] = b;
  }
}

// ---------------- GEMM: A-in-registers, B-in-LDS ring, 1 barrier/iter
// 256x256 tile, BK=64, 8 waves (2M x 4N), per-wave 128x64. A fragments are
// loaded DIRECTLY global->VGPR (16 x dwordx4 per wave per iter; wave pattern
// = 16 rows x 64B full lines, panels L2/L3-resident). B staged via
// global_load_lds into a 3-slot ring (3 x 32KB = 96KB LDS). LDS read traffic
// drops 24 -> 8 b128/wave/iter (R13 decomposition: LDS was ~2800 of the
// ~5800 cyc/iter and serialized against MFMA under 2-wave/SIMD barriers).
// Per iter t: readB(slot t%3) -> stage B(t+2) -> MFMA cluster (per mi: 8
// MFMA then reload aR[mi] for t+1; registers read at issue so no copies)
// -> vmcnt(20) -> barrier.
// vmcnt audit (counter decrements in issue order; intra-iter reordering by
// the compiler is irrelevant because B(t+1)'s 4 ops are the OLDEST
// outstanding and exactly <=20 vmem ops are issued after them in iter t):
// vmcnt(20) retires B(t+1) before iter t+1's bF reads. Tail: t=iters-2 ->
// vmcnt(16); t=iters-1 -> no wait/barrier. aR(t+1) is confirmed by the
// compiler's automatic waits at its MFMA uses (1-iter in-flight window
// ~2500 cyc >> L2 latency). WAR: slot s's reads complete before each wave's
// MFMA(t) which precedes barrier(t); overwrite of s happens at t+1 after
// barrier(t). Chain prologue stages slots 0,1; last-read slot at iters=66
// is 65%3=2 -> no conflict (down is single-tile).
template <int MODE, int ORDER>  // MODE 0 bf16; 1 silu(gbuf)*acc bf16; 2 f32
__global__ __launch_bounds__(512, 2)
void gemm_areg(const short* __restrict__ A, const short* __restrict__ B,
               const short* __restrict__ gbuf, short* __restrict__ outB,
               float* __restrict__ outF, int tilesPerXcd, long ldK, int iters,
               long ldo) {
  extern __shared__ __align__(16) char smem[];   // B ring: 3 x 32 KB

  int xcd = blockIdx.x & 7, loc = blockIdx.x >> 3;
  int tid = threadIdx.x;
  int l = tid & 63, wid = tid >> 6;
  int wr = wid >> 2, wc = wid & 3;      // 2M x 4N waves, 128x64 each
  int lrow = l & 15, lhi = l >> 4, md = lrow & 7;

  const int rr0 = tid >> 3, cc0 = tid & 7;
  const long bOffC = (long)((cc0 ^ (rr0 & 7)) * 8);

  long row0, col0;
  const short* pB; const short* pA;
  auto setTile = [&](int r) {
    int gt = xcd * tilesPerXcd + r;
    int t0 = gt & 15, t1 = gt >> 4;
    int bx = (ORDER == 1) ? t0 : t1;    // gate/up: bx-fastest (B in XCD L2)
    int by = (ORDER == 1) ? t1 : t0;    // down: by-fastest (A panel in L2)
    row0 = (long)bx * 256; col0 = (long)by * 256;
    pB = B + (col0 + rr0) * ldK + bOffC;
    pA = A + (row0 + wr * 128 + lrow) * ldK + lhi * 8;
  };

  auto stB = [&](int slot, int kt) {    // 4 gloads: full 256x64 B K-tile
    char* d = smem + slot * 32768 + tid * 16;
    const short* s = pB + (long)kt * 64;
    gload16(s, d);
    gload16(s + (long)64 * ldK, d + 8192);
    gload16(s + (long)128 * ldK, d + 16384);
    gload16(s + (long)192 * ldK, d + 24576);
  };

  FragCast aR[8][2];
  bf16x8 bF[4][2];
  auto readB = [&](int slot) {
#pragma unroll
    for (int ni = 0; ni < 4; ++ni) {
      const char* base = smem + slot * 32768 + (wc * 64 + ni * 16 + lrow) * 128;
      FragCast f0, f1;
      f0.i = *(const int4*)(base + ((lhi) ^ md) * 16);
      f1.i = *(const int4*)(base + ((4 + lhi) ^ md) * 16);
      bF[ni][0] = f0.b; bF[ni][1] = f1.b;
    }
  };

  f32x4 zr = {0.f, 0.f, 0.f, 0.f};

  int r = loc;
  bool first = true;
  while (r < tilesPerXcd) {
    setTile(r);
    // tile prologue: B(0)->slot0, B(1)->slot1, aR(0). vmcnt(20) leaves
    // [B(1)x4, aR(0)x16] in flight -> confirms B(0) (+ any older stores).
    stB(0, 0); stB(1, 1);
#pragma unroll
    for (int mi = 0; mi < 8; ++mi) {
      const short* s = pA + (long)mi * 16 * ldK;
      aR[mi][0].i = *(const int4*)s;
      aR[mi][1].i = *(const int4*)(s + 32);
    }
    asm volatile("s_waitcnt vmcnt(20)" ::: "memory");
    asm volatile("s_barrier" ::: "memory");
    (void)first; first = false;

    f32x4 acc[8][4];
#pragma unroll
    for (int mi = 0; mi < 8; ++mi)
#pragma unroll
      for (int ni = 0; ni < 4; ++ni) acc[mi][ni] = zr;

    int cur = 0;                        // slot holding B(t)
#pragma unroll 1
    for (int t = 0; t < iters; ++t) {
      readB(cur);
      int st2 = (cur >= 1) ? cur - 1 : 2;          // (cur+2)%3
      if (t + 2 < iters) stB(st2, t + 2);
      __builtin_amdgcn_s_setprio(1);
#pragma unroll
      for (int mi = 0; mi < 8; ++mi) {
#pragma unroll
        for (int ni = 0; ni < 4; ++ni) {
          acc[mi][ni] = __builtin_amdgcn_mfma_f32_16x16x32_bf16(
              aR[mi][0].b, bF[ni][0], acc[mi][ni], 0, 0, 0);
          acc[mi][ni] = __builtin_amdgcn_mfma_f32_16x16x32_bf16(
              aR[mi][1].b, bF[ni][1], acc[mi][ni], 0, 0, 0);
        }
        if (t + 1 < iters) {            // reload aR[mi] for t+1 (regs free)
          const short* s = pA + (long)mi * 16 * ldK + (long)(t + 1) * 64;
          aR[mi][0].i = *(const int4*)s;
          aR[mi][1].i = *(const int4*)(s + 32);
        }
      }
      __builtin_amdgcn_s_setprio(0);
      if (t + 1 < iters) {
        if (t + 2 < iters) asm volatile("s_waitcnt vmcnt(20)" ::: "memory");
        else               asm volatile("s_waitcnt vmcnt(16)" ::: "memory");
        asm volatile("s_barrier" ::: "memory");
      }
      cur = (cur == 2) ? 0 : cur + 1;
    }

    // epilogue: C/D layout col=lane&15, row=(lane>>4)*4+reg  [m89]
#pragma unroll
    for (int mi = 0; mi < 8; ++mi)
#pragma unroll
      for (int ni = 0; ni < 4; ++ni)
#pragma unroll
        for (int j = 0; j < 4; ++j) {
          long grow = row0 + wr * 128 + mi * 16 + lhi * 4 + j;
          long gcol = col0 + wc * 64 + ni * 16 + lrow;
          long idx = grow * ldo + gcol;
          float v = acc[mi][ni][j];
          if constexpr (MODE == 0) {
            outB[idx] = (short)f2bf_bits(v);
          } else if constexpr (MODE == 1) {
            float g = bf2f(gbuf[idx]);
            float t2 = g * (1.f / (1.f + __expf(-g))) * v;   // silu(g)*u
            outB[idx] = (short)f2bf_bits(t2);
          } else {
            outF[idx] = v;
          }
        }
    r += 32;
  }
}

// ---------------------------------------------------------------- launcher
extern "C" void kernel_launch(void* const* d_in, const int* in_sizes, int n_in,
                              void* d_out, int out_size, void* d_ws,
                              size_t ws_size, hipStream_t stream) {
  const float* x       = (const float*)d_in[0];
  const float* gate_w  = (const float*)d_in[1];
  const float* up_w    = (const float*)d_in[2];
  const float* down_w  = (const float*)d_in[3];
  const float* gate_wa = (const float*)d_in[4];
  const float* gate_wb = (const float*)d_in[5];
  const float* up_wa   = (const float*)d_in[6];
  const float* up_wb   = (const float*)d_in[7];
  const float* down_wa = (const float*)d_in[8];
  const float* down_wb = (const float*)d_in[9];
  const int*   seg     = (const int*)d_in[10];

  // ldK gate/up = 4096+128 = 4224 (iters=66); down ld = 11008+64 = 11072 (173)
  char* ws = (char*)d_ws;
  short* xg_pad = (short*)(ws);                   // [4096][4224]  34.6 MB
  short* wA     = (short*)(ws + 34603008);        // gate_w pad -> down_w pad
  short* wB     = (short*)(ws + 127598592);       // up_w pad     93.0 MB
  short* t_pad  = (short*)(ws + 220594176);       // [4096][11072] 90.7 MB

  const int LDS_B = 98304;   // B ring 3 x 32KB
  hipFuncSetAttribute(reinterpret_cast<const void*>(&gemm_areg<0, 1>),
                      hipFuncAttributeMaxDynamicSharedMemorySize, LDS_B);
  hipFuncSetAttribute(reinterpret_cast<const void*>(&gemm_areg<1, 1>),
                      hipFuncAttributeMaxDynamicSharedMemorySize, LDS_B);
  hipFuncSetAttribute(reinterpret_cast<const void*>(&gemm_areg<2, 0>),
                      hipFuncAttributeMaxDynamicSharedMemorySize, LDS_B);

  // bf16 padded operand build (cvt_pad zero-fills the 128-col LoRA tail of
  // the weight matrices; build_wbT then overwrites its 64-col band)
  cvt_pad<<<T_TOK, 256, 0, stream>>>(x, xg_pad, 512, 512, HID, 4224);
  cvt_pad<<<IMD, 256, 0, stream>>>(gate_w, wA, 512, 528, HID, 4224);
  cvt_pad<<<IMD, 256, 0, stream>>>(up_w, wB, 512, 528, HID, 4224);
  build_wbT_pad<<<dim3(43, 64), 256, 0, stream>>>(gate_wb, wA, IMD, 4224, 4096);
  build_wbT_pad<<<dim3(43, 64), 256, 0, stream>>>(up_wb, wB, IMD, 4224, 4160);
  lora_proj<HID, 2><<<T_TOK, 256, 0, stream>>>(
      xg_pad, 4224, gate_wa, up_wa, seg, xg_pad + 4096, 4224, xg_pad + 4160,
      4224);

  // gate (persistent, 86 tiles/XCD): t_pad = x @ gate_w^T + lora_g
  // (LoRA = 2 padded K-tail steps: band1 = xa_g|wbT_g|0, band2 = xa_u|0|wbT_u)
  gemm_areg<0, 1><<<256, 512, LDS_B, stream>>>(
      xg_pad, wA, nullptr, t_pad, nullptr, 86, 4224, 66, 11072);
  // up: t_pad = silu(t_pad) * (x @ up_w^T + lora_u), in place
  gemm_areg<1, 1><<<256, 512, LDS_B, stream>>>(
      xg_pad, wB, t_pad, t_pad, nullptr, 86, 4224, 66, 11072);

  // down operand build (wA region free after gate GEMM)
  cvt_pad<<<T_TOK, 256, 0, stream>>>(down_w, wA, 1376, 1376, IMD, 11072);
  build_wbT_pad<<<dim3(16, 64), 256, 0, stream>>>(down_wb, wA, HID, 11072,
                                                  IMD);
  lora_proj<IMD, 1><<<T_TOK, 256, 0, stream>>>(
      t_pad, 11072, down_wa, nullptr, seg, t_pad + IMD, 11072, nullptr, 64);

  // down: out = t @ down_w^T + lora   [M=4096, N=4096, K'=11072]
  gemm_areg<2, 0><<<256, 512, LDS_B, stream>>>(
      t_pad, wA, nullptr, nullptr, (float*)d_out, 32, 11072, 173, 4096);
}

// Round 16
// 1546.628 us; speedup vs baseline: 5.4751x; 1.9364x over previous
//
#include <hip/hip_runtime.h>

#define T_TOK 4096
#define HID   4096
#define IMD   11008

using f32x4  = __attribute__((ext_vector_type(4))) float;
using bf16x8 = __attribute__((ext_vector_type(8))) __bf16;
union FragCast { int4 i; bf16x8 b; };

__device__ __forceinline__ unsigned f2bf_bits(float f) {
  unsigned u = __float_as_uint(f);
  return (u + 0x7fffu + ((u >> 16) & 1u)) >> 16;   // RNE f32 -> bf16
}
__device__ __forceinline__ float bf2f(short s) {
  return __uint_as_float(((unsigned)(unsigned short)s) << 16);
}
__device__ __forceinline__ int4 cvt8(const float4 f0, const float4 f1) {
  int4 r;
  r.x = f2bf_bits(f0.x) | (f2bf_bits(f0.y) << 16);
  r.y = f2bf_bits(f0.z) | (f2bf_bits(f0.w) << 16);
  r.z = f2bf_bits(f1.x) | (f2bf_bits(f1.y) << 16);
  r.w = f2bf_bits(f1.z) | (f2bf_bits(f1.w) << 16);
  return r;
}
__device__ __forceinline__ void gload16(const void* g, void* l) {
  __builtin_amdgcn_global_load_lds(
      (__attribute__((address_space(1))) void*)g,
      (__attribute__((address_space(3))) void*)l, 16, 0, 0);
}

// ---------------------------------------------------------------- prep kernels
__global__ void cvt_pad(const float* __restrict__ in, short* __restrict__ out,
                        int C8, int CT, long ldin, long ldout) {
  long r = blockIdx.x;
  const float4* s = (const float4*)(in + r * ldin);
  int4* d = (int4*)(out + r * ldout);
  for (int c = threadIdx.x; c < CT; c += blockDim.x)
    d[c] = (c < C8) ? cvt8(s[2 * c], s[2 * c + 1]) : int4{0, 0, 0, 0};
}

__global__ void build_wbT_pad(const float* __restrict__ wb,
                              short* __restrict__ out, int N, long ldout,
                              long K) {
  int n = blockIdx.x * blockDim.x + threadIdx.x;
  int ar = blockIdx.y;
  if (n < N) out[(long)n * ldout + K + ar] = (short)f2bf_bits(wb[(long)ar * N + n]);
}

// per-token rank projection: out[t][a*16+r] = mask * sum_h Abf[t][h]*wa[a][h][r]
template <int KD, int NOUT>
__global__ __launch_bounds__(256)
void lora_proj(const short* __restrict__ Abf, long ldA,
               const float* __restrict__ wa0, const float* __restrict__ wa1,
               const int* __restrict__ seg, short* out0, long ld0, short* out1,
               long ld1) {
  __shared__ __align__(16) short rowbuf[KD];
  __shared__ float part[NOUT][4][16];
  int t = blockIdx.x, tid = threadIdx.x;
  int a = seg[t];
  const int4* src = (const int4*)(Abf + (long)t * ldA);
  for (int c = tid; c < KD / 8; c += 256) ((int4*)rowbuf)[c] = src[c];
  __syncthreads();
  int w = tid >> 6, l = tid & 63;
  int r = l & 15, g = l >> 4;
  const int HW = KD / 4;
  float s0 = 0.f, s1 = 0.f;
  const float* p0 = wa0 + (long)a * KD * 16 + r;
  const float* p1 = (NOUT == 2) ? (wa1 + (long)a * KD * 16 + r) : nullptr;
  int h = w * HW + g;
  for (int k = 0; k < HW / 4; ++k, h += 4) {
    float xv = bf2f(rowbuf[h]);
    s0 = fmaf(xv, p0[(long)h * 16], s0);
    if (NOUT == 2) s1 = fmaf(xv, p1[(long)h * 16], s1);
  }
  s0 += __shfl_xor(s0, 16); s0 += __shfl_xor(s0, 32);
  if (NOUT == 2) { s1 += __shfl_xor(s1, 16); s1 += __shfl_xor(s1, 32); }
  if (l < 16) { part[0][w][r] = s0; if (NOUT == 2) part[1][w][r] = s1; }
  __syncthreads();
  if (tid < 64 * NOUT) {
    int m = tid >> 6, ar = tid & 63;
    float v = 0.f;
    if ((ar >> 4) == a) {
      int r2 = ar & 15;
      v = part[m][0][r2] + part[m][1][r2] + part[m][2][r2] + part[m][3][r2];
    }
    short b = (short)f2bf_bits(v);
    if (m == 0) out0[(long)t * ld0 + ar] = b;
    else        out1[(long)t * ld1 + ar] = b;
  }
}

// ---- CHAINED gate->up GEMM: persistent, 2-phase/K-step, 2 barriers/iter
// R13 structure with phases halved (4 -> 2; barrier-reduction is the only
// schedule knob that has measurably helped: R12->R13 = +4.5%). Per iter:
//  phA: read bF(8 b128) + aL(8) | stage B(t+1) (4 gloads) | BAR | 32 MFMA(mi0-3)
//  phB: read aH(8)              | stage A(t+2) (4 gloads) | vmcnt(4) | BAR
//       | 32 MFMA(mi4-7)
// vmcnt audit: queue at phB wait = [A(t+1)4, B(t+1)4, A(t+2)4] -> vmcnt(4)
// confirms A(t+1),B(t+1) (read next iter), keeps A(t+2) flying; t=iters-2 ->
// vmcnt(0); t=iters-1 -> skip wait+BAR2. WAR (pre-MFMA barriers only):
// stage-B(t+1) issues after BAR2(t-1); BAR2(t-1) arrival implies every wave
// issued MFMA-A(t-1), which (compiler lgkm wait) implies its bF(t-1) reads
// RETIRED -> overwrite safe. stage-A(t+2) issues after BAR1(t); arrival at
// BAR1(t) implies MFMA-B(t-1) issued -> aH(t-1) reads retired. Same at tile
// and pass boundaries (prologue vmcnt(4)+BAR).
// CHAINING: each persistent block runs pass0 (gate, B=wGate, write t_pad
// bf16) then pass1 (up, B=wUp, epilogue reads ITS OWN t_pad tile -- pass1's
// prologue vmcnt(4) retires pass0's stores (older in queue), same CU -> same
// XCD L2 -> coherent & L2-hot) for each of its tiles. Up's A-panel staging
// is also L2-hot from pass0.
__global__ __launch_bounds__(512, 2)
void gemm_guc(const short* __restrict__ A, const short* __restrict__ Bg,
              const short* __restrict__ Bu, short* __restrict__ tpad,
              int tilesPerXcd, long ldK, int iters, long ldo) {
  extern __shared__ __align__(16) char smem[];
  // A ring: 3 x 32KB @0; B dbuf: 2 x 32KB @98304  (160 KB)

  int xcd = blockIdx.x & 7, loc = blockIdx.x >> 3;
  int tid = threadIdx.x;
  int l = tid & 63, wid = tid >> 6;
  int wr = wid >> 2, wc = wid & 3;      // 2M x 4N waves, 128x64 each
  int lrow = l & 15, lhi = l >> 4, md = lrow & 7;
  const int rr0 = tid >> 3;
  const long cOff = (long)(((tid & 7) ^ (rr0 & 7)) * 8);

  const int csel0 = (lhi ^ md) * 16;
  const int csel1 = ((4 + lhi) ^ md) * 16;

  long row0, col0;
  const short* pA; const short* pB;

  auto stA = [&](int bi, int h, int kt) {
    char* d = smem + bi * 32768 + tid * 16;
    const short* s = pA + (long)kt * 64 + (long)(2 * h) * 64 * ldK;
    gload16(s, d + (2 * h) * 8192);
    gload16(s + (long)64 * ldK, d + (2 * h + 1) * 8192);
  };
  auto stB = [&](int bi, int h, int kt) {
    char* d = smem + 98304 + bi * 32768 + tid * 16;
    const short* s = pB + (long)kt * 64 + (long)(2 * h) * 64 * ldK;
    gload16(s, d + (2 * h) * 8192);
    gload16(s + (long)64 * ldK, d + (2 * h + 1) * 8192);
  };

  f32x4 zr = {0.f, 0.f, 0.f, 0.f};

  for (int r = loc; r < tilesPerXcd; r += 32) {
    int gt = xcd * tilesPerXcd + r;
    row0 = (long)(gt & 15) * 256;       // bx-fastest: B col-panel in XCD L2
    col0 = (long)(gt >> 4) * 256;
    pA = A + (row0 + rr0) * ldK + cOff;

    for (int pass = 0; pass < 2; ++pass) {
      pB = (pass ? Bu : Bg) + (col0 + rr0) * ldK + cOff;

      // prologue: A(0), B(0), A(1); vmcnt(4) retires older ops (incl. the
      // previous pass's t_pad stores) and confirms A(0),B(0).
      stA(0, 0, 0); stA(0, 1, 0);
      stB(0, 0, 0); stB(0, 1, 0);
      stA(1, 0, 1); stA(1, 1, 1);
      asm volatile("s_waitcnt vmcnt(4)" ::: "memory");
      asm volatile("s_barrier" ::: "memory");

      f32x4 acc[8][4];
#pragma unroll
      for (int mi = 0; mi < 8; ++mi)
#pragma unroll
        for (int ni = 0; ni < 4; ++ni) acc[mi][ni] = zr;

      int ca = 0;
#pragma unroll 1
      for (int t = 0; t < iters; ++t) {
        const char* Ab = smem + ca * 32768;
        const char* Bb = smem + 98304 + (t & 1) * 32768;
        int na2 = (ca >= 1) ? ca - 1 : 2;   // (ca+2)%3
        int nb1 = (t + 1) & 1;

        // ---- phase A: bF + aL reads; stage B(t+1); BAR; MFMA mi0-3
        bf16x8 bF[4][2], aL[4][2];
#pragma unroll
        for (int ni = 0; ni < 4; ++ni) {
          const char* base = Bb + (wc * 64 + ni * 16 + lrow) * 128;
          FragCast f0, f1;
          f0.i = *(const int4*)(base + csel0);
          f1.i = *(const int4*)(base + csel1);
          bF[ni][0] = f0.b; bF[ni][1] = f1.b;
        }
#pragma unroll
        for (int m2 = 0; m2 < 4; ++m2) {
          const char* base = Ab + (wr * 128 + m2 * 16 + lrow) * 128;
          FragCast f0, f1;
          f0.i = *(const int4*)(base + csel0);
          f1.i = *(const int4*)(base + csel1);
          aL[m2][0] = f0.b; aL[m2][1] = f1.b;
        }
        if (t + 1 < iters) { stB(nb1, 0, t + 1); stB(nb1, 1, t + 1); }
        asm volatile("s_barrier" ::: "memory");
        __builtin_amdgcn_s_setprio(1);
#pragma unroll
        for (int k = 0; k < 2; ++k)
#pragma unroll
          for (int m2 = 0; m2 < 4; ++m2)
#pragma unroll
            for (int ni = 0; ni < 4; ++ni)
              acc[m2][ni] = __builtin_amdgcn_mfma_f32_16x16x32_bf16(
                  aL[m2][k], bF[ni][k], acc[m2][ni], 0, 0, 0);
        __builtin_amdgcn_s_setprio(0);

        // ---- phase B: aH reads; stage A(t+2); counted wait; BAR; MFMA mi4-7
        bf16x8 aH[4][2];
#pragma unroll
        for (int m2 = 0; m2 < 4; ++m2) {
          const char* base = Ab + (wr * 128 + 64 + m2 * 16 + lrow) * 128;
          FragCast f0, f1;
          f0.i = *(const int4*)(base + csel0);
          f1.i = *(const int4*)(base + csel1);
          aH[m2][0] = f0.b; aH[m2][1] = f1.b;
        }
        if (t + 2 < iters) {
          stA(na2, 0, t + 2); stA(na2, 1, t + 2);
          asm volatile("s_waitcnt vmcnt(4)" ::: "memory");
          asm volatile("s_barrier" ::: "memory");
        } else if (t + 1 < iters) {
          asm volatile("s_waitcnt vmcnt(0)" ::: "memory");
          asm volatile("s_barrier" ::: "memory");
        }
        __builtin_amdgcn_s_setprio(1);
#pragma unroll
        for (int k = 0; k < 2; ++k)
#pragma unroll
          for (int m2 = 0; m2 < 4; ++m2)
#pragma unroll
            for (int ni = 0; ni < 4; ++ni)
              acc[4 + m2][ni] = __builtin_amdgcn_mfma_f32_16x16x32_bf16(
                  aH[m2][k], bF[ni][k], acc[4 + m2][ni], 0, 0, 0);
        __builtin_amdgcn_s_setprio(0);
        ca = (ca == 2) ? 0 : ca + 1;
      }

      // epilogue: C/D layout col=lane&15, row=(lane>>4)*4+reg  [m89]
#pragma unroll
      for (int mi = 0; mi < 8; ++mi)
#pragma unroll
        for (int ni = 0; ni < 4; ++ni)
#pragma unroll
          for (int j = 0; j < 4; ++j) {
            long grow = row0 + wr * 128 + mi * 16 + lhi * 4 + j;
            long gcol = col0 + wc * 64 + ni * 16 + lrow;
            long idx = grow * ldo + gcol;
            float v = acc[mi][ni][j];
            if (pass == 0) {
              tpad[idx] = (short)f2bf_bits(v);
            } else {
              float g = bf2f(tpad[idx]);        // own pass-0 write, L2-hot
              float t2 = g * (1.f / (1.f + __expf(-g))) * v;   // silu(g)*u
              tpad[idx] = (short)f2bf_bits(t2);
            }
          }
    }
  }
}

// --------------------- down GEMM: same 2-phase loop, single tile per block
__global__ __launch_bounds__(512, 2)
void gemm_down(const short* __restrict__ A, const short* __restrict__ B,
               float* __restrict__ outF, int nby, long ldK, int iters,
               long ldo) {
  extern __shared__ __align__(16) char smem[];

  int nwg = gridDim.x;
  int orig = blockIdx.x;
  int q = nwg >> 3, rr = nwg & 7;
  int xcd = orig & 7, loc = orig >> 3;
  int swz = (xcd < rr ? xcd * (q + 1) : rr * (q + 1) + (xcd - rr) * q) + loc;
  int by = swz % nby, bx = swz / nby;
  long row0 = (long)bx * 256, col0 = (long)by * 256;

  int tid = threadIdx.x;
  int l = tid & 63, wid = tid >> 6;
  int wr = wid >> 2, wc = wid & 3;
  int lrow = l & 15, lhi = l >> 4, md = lrow & 7;
  const int rr0 = tid >> 3;
  const long cOff = (long)(((tid & 7) ^ (rr0 & 7)) * 8);

  const int csel0 = (lhi ^ md) * 16;
  const int csel1 = ((4 + lhi) ^ md) * 16;

  const short* pA = A + (row0 + rr0) * ldK + cOff;
  const short* pB = B + (col0 + rr0) * ldK + cOff;

  auto stA = [&](int bi, int h, int kt) {
    char* d = smem + bi * 32768 + tid * 16;
    const short* s = pA + (long)kt * 64 + (long)(2 * h) * 64 * ldK;
    gload16(s, d + (2 * h) * 8192);
    gload16(s + (long)64 * ldK, d + (2 * h + 1) * 8192);
  };
  auto stB = [&](int bi, int h, int kt) {
    char* d = smem + 98304 + bi * 32768 + tid * 16;
    const short* s = pB + (long)kt * 64 + (long)(2 * h) * 64 * ldK;
    gload16(s, d + (2 * h) * 8192);
    gload16(s + (long)64 * ldK, d + (2 * h + 1) * 8192);
  };

  f32x4 acc[8][4];
  f32x4 zr = {0.f, 0.f, 0.f, 0.f};
#pragma unroll
  for (int mi = 0; mi < 8; ++mi)
#pragma unroll
    for (int ni = 0; ni < 4; ++ni) acc[mi][ni] = zr;

  stA(0, 0, 0); stA(0, 1, 0);
  stB(0, 0, 0); stB(0, 1, 0);
  stA(1, 0, 1); stA(1, 1, 1);
  asm volatile("s_waitcnt vmcnt(4)" ::: "memory");
  asm volatile("s_barrier" ::: "memory");

  int ca = 0;
#pragma unroll 1
  for (int t = 0; t < iters; ++t) {
    const char* Ab = smem + ca * 32768;
    const char* Bb = smem + 98304 + (t & 1) * 32768;
    int na2 = (ca >= 1) ? ca - 1 : 2;
    int nb1 = (t + 1) & 1;

    bf16x8 bF[4][2], aL[4][2];
#pragma unroll
    for (int ni = 0; ni < 4; ++ni) {
      const char* base = Bb + (wc * 64 + ni * 16 + lrow) * 128;
      FragCast f0, f1;
      f0.i = *(const int4*)(base + csel0);
      f1.i = *(const int4*)(base + csel1);
      bF[ni][0] = f0.b; bF[ni][1] = f1.b;
    }
#pragma unroll
    for (int m2 = 0; m2 < 4; ++m2) {
      const char* base = Ab + (wr * 128 + m2 * 16 + lrow) * 128;
      FragCast f0, f1;
      f0.i = *(const int4*)(base + csel0);
      f1.i = *(const int4*)(base + csel1);
      aL[m2][0] = f0.b; aL[m2][1] = f1.b;
    }
    if (t + 1 < iters) { stB(nb1, 0, t + 1); stB(nb1, 1, t + 1); }
    asm volatile("s_barrier" ::: "memory");
    __builtin_amdgcn_s_setprio(1);
#pragma unroll
    for (int k = 0; k < 2; ++k)
#pragma unroll
      for (int m2 = 0; m2 < 4; ++m2)
#pragma unroll
        for (int ni = 0; ni < 4; ++ni)
          acc[m2][ni] = __builtin_amdgcn_mfma_f32_16x16x32_bf16(
              aL[m2][k], bF[ni][k], acc[m2][ni], 0, 0, 0);
    __builtin_amdgcn_s_setprio(0);

    bf16x8 aH[4][2];
#pragma unroll
    for (int m2 = 0; m2 < 4; ++m2) {
      const char* base = Ab + (wr * 128 + 64 + m2 * 16 + lrow) * 128;
      FragCast f0, f1;
      f0.i = *(const int4*)(base + csel0);
      f1.i = *(const int4*)(base + csel1);
      aH[m2][0] = f0.b; aH[m2][1] = f1.b;
    }
    if (t + 2 < iters) {
      stA(na2, 0, t + 2); stA(na2, 1, t + 2);
      asm volatile("s_waitcnt vmcnt(4)" ::: "memory");
      asm volatile("s_barrier" ::: "memory");
    } else if (t + 1 < iters) {
      asm volatile("s_waitcnt vmcnt(0)" ::: "memory");
      asm volatile("s_barrier" ::: "memory");
    }
    __builtin_amdgcn_s_setprio(1);
#pragma unroll
    for (int k = 0; k < 2; ++k)
#pragma unroll
      for (int m2 = 0; m2 < 4; ++m2)
#pragma unroll
        for (int ni = 0; ni < 4; ++ni)
          acc[4 + m2][ni] = __builtin_amdgcn_mfma_f32_16x16x32_bf16(
              aH[m2][k], bF[ni][k], acc[4 + m2][ni], 0, 0, 0);
    __builtin_amdgcn_s_setprio(0);
    ca = (ca == 2) ? 0 : ca + 1;
  }

#pragma unroll
  for (int mi = 0; mi < 8; ++mi)
#pragma unroll
    for (int ni = 0; ni < 4; ++ni)
#pragma unroll
      for (int j = 0; j < 4; ++j) {
        long grow = row0 + wr * 128 + mi * 16 + lhi * 4 + j;
        long gcol = col0 + wc * 64 + ni * 16 + lrow;
        outF[grow * ldo + gcol] = acc[mi][ni][j];
      }
}

// ---------------------------------------------------------------- launcher
extern "C" void kernel_launch(void* const* d_in, const int* in_sizes, int n_in,
                              void* d_out, int out_size, void* d_ws,
                              size_t ws_size, hipStream_t stream) {
  const float* x       = (const float*)d_in[0];
  const float* gate_w  = (const float*)d_in[1];
  const float* up_w    = (const float*)d_in[2];
  const float* down_w  = (const float*)d_in[3];
  const float* gate_wa = (const float*)d_in[4];
  const float* gate_wb = (const float*)d_in[5];
  const float* up_wa   = (const float*)d_in[6];
  const float* up_wb   = (const float*)d_in[7];
  const float* down_wa = (const float*)d_in[8];
  const float* down_wb = (const float*)d_in[9];
  const int*   seg     = (const int*)d_in[10];

  // ldK gate/up = 4096+128 = 4224 (iters=66); down ld = 11008+64 = 11072 (173)
  char* ws = (char*)d_ws;
  short* xg_pad = (short*)(ws);                   // [4096][4224]  34.6 MB
  short* wA     = (short*)(ws + 34603008);        // gate_w pad -> down_w pad
  short* wB     = (short*)(ws + 127598592);       // up_w pad     93.0 MB
  short* t_pad  = (short*)(ws + 220594176);       // [4096][11072] 90.7 MB

  const int LDS_G = 163840;   // A 3x32K + B 2x32K
  hipFuncSetAttribute(reinterpret_cast<const void*>(&gemm_guc),
                      hipFuncAttributeMaxDynamicSharedMemorySize, LDS_G);
  hipFuncSetAttribute(reinterpret_cast<const void*>(&gemm_down),
                      hipFuncAttributeMaxDynamicSharedMemorySize, LDS_G);

  // bf16 padded operand build (cvt_pad zero-fills the 128-col LoRA tail of
  // the weight matrices; build_wbT then overwrites its 64-col band)
  cvt_pad<<<T_TOK, 256, 0, stream>>>(x, xg_pad, 512, 512, HID, 4224);
  cvt_pad<<<IMD, 256, 0, stream>>>(gate_w, wA, 512, 528, HID, 4224);
  cvt_pad<<<IMD, 256, 0, stream>>>(up_w, wB, 512, 528, HID, 4224);
  build_wbT_pad<<<dim3(43, 64), 256, 0, stream>>>(gate_wb, wA, IMD, 4224, 4096);
  build_wbT_pad<<<dim3(43, 64), 256, 0, stream>>>(up_wb, wB, IMD, 4224, 4160);
  lora_proj<HID, 2><<<T_TOK, 256, 0, stream>>>(
      xg_pad, 4224, gate_wa, up_wa, seg, xg_pad + 4096, 4224, xg_pad + 4160,
      4224);

  // chained gate->up (persistent): pass0 t_pad = x@gw^T+lg; pass1 in-place
  // t_pad = silu(t_pad) * (x@uw^T+lu). LoRA = 2 padded K-tail steps
  // (band1 = xa_g|wbT_g|0, band2 = xa_u|0|wbT_u).
  gemm_guc<<<256, 512, LDS_G, stream>>>(xg_pad, wA, wB, t_pad,
                                        86, 4224, 66, 11072);

  // down operand build (wA region free after gate pass)
  cvt_pad<<<T_TOK, 256, 0, stream>>>(down_w, wA, 1376, 1376, IMD, 11072);
  build_wbT_pad<<<dim3(16, 64), 256, 0, stream>>>(down_wb, wA, HID, 11072,
                                                  IMD);
  lora_proj<IMD, 1><<<T_TOK, 256, 0, stream>>>(
      t_pad, 11072, down_wa, nullptr, seg, t_pad + IMD, 11072, nullptr, 64);

  // down: out = t @ down_w^T + lora   [M=4096, N=4096, K'=11072]
  gemm_down<<<16 * 16, 512, LDS_G, stream>>>(t_pad, wA, (float*)d_out, 16,
                                             11072, 173, 4096);
}